// Round 8
// baseline (342.550 us; speedup 1.0000x reference)
//
#include <hip/hip_runtime.h>
#include <hip/hip_bf16.h>
#include <hip/hip_cooperative_groups.h>

namespace cg = cooperative_groups;

#define NEG_SLOPE 0.2f
#define BSH   6        // bucket = 64 dst nodes
#define BUKSZ 64
#define MAXBUK 1024    // supports N <= 65536 (and src ids fit in ushort)
#define CHUNK 4096     // edges per partition block
#define BCAP  2048     // LDS capacity per bucket in csr phase (mean ~1024, 2x headroom)
#define XPAD  136      // LDS row stride (128 + 8): 272 B rows, 16B-aligned, breaks bank aliasing

typedef __attribute__((ext_vector_type(8))) short bf16x8;   // 8 bf16 = 4 VGPRs
typedef __attribute__((ext_vector_type(4))) float f32x4;    // MFMA C/D

__device__ __forceinline__ float lrelu(float v) {
    return v > 0.f ? v : NEG_SLOPE * v;
}

__device__ __forceinline__ unsigned short f2bf(float f) {   // RNE float->bf16
    unsigned int u = __float_as_uint(f);
    u = (u + 0x7fffu + ((u >> 16) & 1u)) >> 16;
    return (unsigned short)u;
}

__device__ __forceinline__ float2 bfpair(unsigned int u) {  // 2 packed bf16 -> 2 floats
    float2 r;
    r.x = __uint_as_float(u << 16);
    r.y = __uint_as_float(u & 0xffff0000u);
    return r;
}

// ---------------------------------------------------------------------------
// K1 (MFMA): h1b[N,128] (bf16) = x @ W1 via mfma_f32_16x16x32_bf16.
// W1 (fp32, k-major) converted to bf16 n-major in LDS per block (L2-resident
// source, ~free). Block: 256 thr = 4 waves; 64 rows/block.
// Fused epilogue: a_s1/a_d1 head dots + coalesced bf16 h1b store via LDS.
// ---------------------------------------------------------------------------
__global__ __launch_bounds__(256) void k1_mfma(const float* __restrict__ x,
                                               const float* __restrict__ W1,
                                               const float* __restrict__ a_src1,
                                               const float* __restrict__ a_dst1,
                                               unsigned short* __restrict__ h1b,
                                               float* __restrict__ a_s1,
                                               float* __restrict__ a_d1, int n) {
    __shared__ unsigned short xsh[64 * XPAD];    // x tile bf16 (17.4 KB)
    __shared__ unsigned short wsh[128 * XPAD];   // W1^T bf16 (34.8 KB)
    const int tid = threadIdx.x;
    const int row0 = blockIdx.x * 64;
    // stage W1 -> wsh[n*XPAD+k] (coalesced fp32 read, LDS scatter 2-way-free)
#pragma unroll
    for (int i = tid; i < 128 * 128; i += 256) {
        int k = i >> 7, nn = i & 127;
        wsh[nn * XPAD + k] = f2bf(W1[i]);
    }
    // stage x: 64 rows x 128 k, fp32 -> bf16 (8 float4 per thread)
#pragma unroll
    for (int i = 0; i < 8; ++i) {
        int idx = tid + i * 256;          // float4 index 0..2047 (32 per row)
        int r = idx >> 5;
        int c = (idx & 31) * 4;
        int gr = row0 + r;
        float4 v = make_float4(0.f, 0.f, 0.f, 0.f);
        if (gr < n) v = *(const float4*)&x[(size_t)gr * 128 + c];
        ushort4 b;
        b.x = f2bf(v.x); b.y = f2bf(v.y); b.z = f2bf(v.z); b.w = f2bf(v.w);
        *(ushort4*)&xsh[r * XPAD + c] = b;
    }
    __syncthreads();

    const int wave = tid >> 6;
    const int lane = tid & 63;
    const int quad = lane >> 4;
    const int l16 = lane & 15;

    // A fragments: m = l16 (row within wave strip), k = ks*32 + quad*8
    bf16x8 afrag[4];
#pragma unroll
    for (int ks = 0; ks < 4; ++ks)
        afrag[ks] = *(const bf16x8*)&xsh[(wave * 16 + l16) * XPAD + ks * 32 + quad * 8];

    f32x4 acc[8];
#pragma unroll
    for (int t = 0; t < 8; ++t) acc[t] = (f32x4){0.f, 0.f, 0.f, 0.f};

#pragma unroll
    for (int t = 0; t < 8; ++t) {         // n-tiles: cols t*16 .. t*16+15
#pragma unroll
        for (int ks = 0; ks < 4; ++ks) {
            bf16x8 bfrag = *(const bf16x8*)&wsh[(t * 16 + l16) * XPAD + ks * 32 + quad * 8];
            acc[t] = __builtin_amdgcn_mfma_f32_16x16x32_bf16(afrag[ks], bfrag, acc[t], 0, 0, 0);
        }
    }

    // --- attention-dot epilogue (fp32 from accumulators) ---
    float hs[4][4], hd[4][4];             // [head][reg]
#pragma unroll
    for (int h = 0; h < 4; ++h)
#pragma unroll
        for (int r = 0; r < 4; ++r) { hs[h][r] = 0.f; hd[h][r] = 0.f; }
#pragma unroll
    for (int t = 0; t < 8; ++t) {
        float as = a_src1[t * 16 + l16];
        float advv = a_dst1[t * 16 + l16];
#pragma unroll
        for (int r = 0; r < 4; ++r) {
            float ps = acc[t][r] * as;
            float pd = acc[t][r] * advv;
#pragma unroll
            for (int off = 1; off < 16; off <<= 1) {
                ps += __shfl_xor(ps, off);
                pd += __shfl_xor(pd, off);
            }
            hs[t >> 1][r] += ps;
            hd[t >> 1][r] += pd;
        }
    }
    if (l16 < 4) {                        // lane l16 writes head h=l16
        int h = l16;
#pragma unroll
        for (int r = 0; r < 4; ++r) {
            int gr = row0 + wave * 16 + quad * 4 + r;
            if (gr < n) {
                a_s1[gr * 4 + h] = hs[h][r];
                a_d1[gr * 4 + h] = hd[h][r];
            }
        }
    }

    // --- h1b store via LDS (coalesced ushort4) ---
    __syncthreads();                      // xsh dead (afrag consumed)
#pragma unroll
    for (int t = 0; t < 8; ++t)
#pragma unroll
        for (int r = 0; r < 4; ++r)
            xsh[(wave * 16 + quad * 4 + r) * XPAD + t * 16 + l16] = f2bf(acc[t][r]);
    __syncthreads();
#pragma unroll
    for (int i = 0; i < 8; ++i) {
        int idx = tid + i * 256;          // ushort4 index 0..2047 (32 per row)
        int r = idx >> 5;
        int c = (idx & 31) * 4;
        int gr = row0 + r;
        if (gr < n)
            *(ushort4*)&h1b[(size_t)gr * 128 + c] = *(ushort4*)&xsh[r * XPAD + c];
    }
}

// ---------------------------------------------------------------------------
// K_PART (cooperative): full CSR build in ONE kernel.
// Grid = nblk (196) blocks x 256 thr, trivially co-resident (9 KB LDS).
// Phases separated by grid.sync():
//   1 hist: per-chunk bucket histogram -> mat[chunk][bucket]
//   2 colscan: exclusive scan over chunks per bucket (in place) + btot
//   3 bucketscan: exclusive scan of btot -> bbase (block 0)
//   4 place: LDS cursors -> part[] packed (src<<16 | dst low16)
//   5 csr: per-bucket node sort in LDS -> row_start + csr_src (ushort)
// ---------------------------------------------------------------------------
__global__ __launch_bounds__(256) void k_part(const int* __restrict__ src,
                                              const int* __restrict__ dst, int e,
                                              int nbuk, int nblk,
                                              int* __restrict__ mat,
                                              int* __restrict__ btot,
                                              int* __restrict__ bbase,
                                              unsigned int* __restrict__ part,
                                              int* __restrict__ row_start,
                                              unsigned short* __restrict__ csr_src) {
    __shared__ int lcnt[MAXBUK];          // hist counts / place cursors
    __shared__ unsigned short ls[BCAP];   // csr staging
    __shared__ int cnt[64];
    __shared__ int cur[64];
    __shared__ int s[256];
    __shared__ int carry;
    cg::grid_group grid = cg::this_grid();
    const int bid = blockIdx.x;
    const int tid = threadIdx.x;
    const int e0 = bid * CHUNK;
    const int e1 = min(e, e0 + CHUNK);

    // ---- phase 1: histogram
    for (int b = tid; b < nbuk; b += 256) lcnt[b] = 0;
    __syncthreads();
    for (int k = e0 + tid; k < e1; k += 256)
        atomicAdd(&lcnt[dst[k] >> BSH], 1);
    __syncthreads();
    for (int b = tid; b < nbuk; b += 256)
        mat[bid * nbuk + b] = lcnt[b];    // coalesced row write
    grid.sync();

    // ---- phase 2: column scan (thread per bucket; coalesced across threads)
    {
        int b = bid * 256 + tid;
        if (b < nbuk) {
            int run = 0;
            for (int i = 0; i < nblk; ++i) {
                int idx = i * nbuk + b;
                int t = mat[idx];
                mat[idx] = run;
                run += t;
            }
            btot[b] = run;
        }
    }
    grid.sync();

    // ---- phase 3: bucket-total exclusive scan (block 0)
    if (bid == 0) {
        if (tid == 0) carry = 0;
        __syncthreads();
        for (int base = 0; base < nbuk; base += 256) {
            int g = base + tid;
            int v = (g < nbuk) ? btot[g] : 0;
            s[tid] = v;
            __syncthreads();
            for (int off = 1; off < 256; off <<= 1) {
                int t = (tid >= off) ? s[tid - off] : 0;
                __syncthreads();
                s[tid] += t;
                __syncthreads();
            }
            if (g < nbuk) bbase[g] = carry + s[tid] - v;   // exclusive
            __syncthreads();
            if (tid == 255) carry += s[255];
            __syncthreads();
        }
        if (tid == 0) bbase[nbuk] = carry;
    }
    grid.sync();

    // ---- phase 4: placement
    for (int b = tid; b < nbuk; b += 256)
        lcnt[b] = bbase[b] + mat[bid * nbuk + b];
    __syncthreads();
    for (int k = e0 + tid; k < e1; k += 256) {
        int d = dst[k];
        int pos = atomicAdd(&lcnt[d >> BSH], 1);
        part[pos] = ((unsigned int)src[k] << 16) | (unsigned int)(d & 0xffff);
    }
    grid.sync();

    // ---- phase 5: per-bucket CSR finalize (block handles buckets bid, bid+G, ...)
    for (int b = bid; b < nbuk; b += gridDim.x) {
        const int eb = bbase[b];
        const int nE = bbase[b + 1] - eb;
        if (tid < 64) cnt[tid] = 0;
        __syncthreads();
        for (int k = tid; k < nE; k += 256)
            atomicAdd(&cnt[part[eb + k] & 63u], 1);
        __syncthreads();
        if (tid < 64) {                   // wave-0 exclusive scan of 64 counts
            int v = cnt[tid];
            int incl = v;
#pragma unroll
            for (int off = 1; off < 64; off <<= 1) {
                int t = __shfl_up(incl, off);
                if (tid >= off) incl += t;
            }
            int excl = incl - v;
            cur[tid] = excl;
            row_start[(b << BSH) + tid] = eb + excl;
            if (tid == 63 && b == nbuk - 1) row_start[(b << BSH) + 64] = eb + incl;
        }
        __syncthreads();
        for (int k = tid; k < nE; k += 256) {
            unsigned int u = part[eb + k];
            int pos = atomicAdd(&cur[u & 63u], 1);
            if (pos < BCAP) ls[pos] = (unsigned short)(u >> 16);
        }
        __syncthreads();
        for (int k = tid; k < nE; k += 256)
            csr_src[eb + k] = ls[k];      // coalesced
        __syncthreads();
    }
}

// ---------------------------------------------------------------------------
// K3: layer-1 softmax-aggregation, flat: one wave per dst node.
// Quarter-wave per edge, PREDICATED uniform unroll-4 (16 gather chains/wave,
// deg<=16 completes edge loop in one iteration; pad slots clamp to deg-1 with
// zero weight). Lane owns 8 bf16 channels (16B gather). No max shift.
// Fused: +bias, relu, layer-2 projection, layer-2 attn dots -> pk.
// ---------------------------------------------------------------------------
__global__ __launch_bounds__(256) void k3_agg1(
    const unsigned short* __restrict__ h1b, const float* __restrict__ a_s1,
    const float* __restrict__ a_d1, const int* __restrict__ row_start,
    const unsigned short* __restrict__ csr_src, const float* __restrict__ b1,
    const float* __restrict__ W2, const float* __restrict__ a_src2,
    const float* __restrict__ a_dst2, float4* __restrict__ pk, int n) {
    const int wid = (blockIdx.x * blockDim.x + threadIdx.x) >> 6;
    const int lane = threadIdx.x & 63;
    if (wid >= n) return;
    const int q = lane >> 4;             // quarter: edge slot 0..3
    const int l16 = lane & 15;
    const int c0 = l16 * 8;              // 8 channels per lane
    const int head = l16 >> 2;           // 4 lanes per head
    const int rs = row_start[wid];
    const int deg = row_start[wid + 1] - rs;
    const float ad = a_d1[wid * 4 + head];

    float dnm = 0.f;
    float acc[8] = {};
    const int dm1 = deg - 1;
    const int rounded = (deg + 15) & ~15;
    for (int j = q; j < rounded; j += 16) {   // 4 predicated slots per quarter
        int i0 = min(j,      dm1);
        int i1 = min(j + 4,  dm1);
        int i2 = min(j + 8,  dm1);
        int i3 = min(j + 12, dm1);
        int s0 = (int)csr_src[rs + i0];
        int s1 = (int)csr_src[rs + i1];
        int s2 = (int)csr_src[rs + i2];
        int s3 = (int)csr_src[rs + i3];
        float as0 = a_s1[s0 * 4 + head];
        float as1 = a_s1[s1 * 4 + head];
        float as2 = a_s1[s2 * 4 + head];
        float as3 = a_s1[s3 * 4 + head];
        uint4 g0 = *(const uint4*)&h1b[(size_t)s0 * 128 + c0];
        uint4 g1 = *(const uint4*)&h1b[(size_t)s1 * 128 + c0];
        uint4 g2 = *(const uint4*)&h1b[(size_t)s2 * 128 + c0];
        uint4 g3 = *(const uint4*)&h1b[(size_t)s3 * 128 + c0];
        float p0 = (j      < deg) ? __expf(lrelu(as0 + ad)) : 0.f;
        float p1 = (j + 4  < deg) ? __expf(lrelu(as1 + ad)) : 0.f;
        float p2 = (j + 8  < deg) ? __expf(lrelu(as2 + ad)) : 0.f;
        float p3 = (j + 12 < deg) ? __expf(lrelu(as3 + ad)) : 0.f;
        dnm += (p0 + p1) + (p2 + p3);
        float2 v0a = bfpair(g0.x), v0b = bfpair(g0.y), v0c = bfpair(g0.z), v0d = bfpair(g0.w);
        float2 v1a = bfpair(g1.x), v1b = bfpair(g1.y), v1c = bfpair(g1.z), v1d = bfpair(g1.w);
        float2 v2a = bfpair(g2.x), v2b = bfpair(g2.y), v2c = bfpair(g2.z), v2d = bfpair(g2.w);
        float2 v3a = bfpair(g3.x), v3b = bfpair(g3.y), v3c = bfpair(g3.z), v3d = bfpair(g3.w);
        acc[0] += (p0 * v0a.x + p1 * v1a.x) + (p2 * v2a.x + p3 * v3a.x);
        acc[1] += (p0 * v0a.y + p1 * v1a.y) + (p2 * v2a.y + p3 * v3a.y);
        acc[2] += (p0 * v0b.x + p1 * v1b.x) + (p2 * v2b.x + p3 * v3b.x);
        acc[3] += (p0 * v0b.y + p1 * v1b.y) + (p2 * v2b.y + p3 * v3b.y);
        acc[4] += (p0 * v0c.x + p1 * v1c.x) + (p2 * v2c.x + p3 * v3c.x);
        acc[5] += (p0 * v0c.y + p1 * v1c.y) + (p2 * v2c.y + p3 * v3c.y);
        acc[6] += (p0 * v0d.x + p1 * v1d.x) + (p2 * v2d.x + p3 * v3d.x);
        acc[7] += (p0 * v0d.y + p1 * v1d.y) + (p2 * v2d.y + p3 * v3d.y);
    }
    // combine quarters (lanes l16, l16+16, l16+32, l16+48 share channels/head)
    dnm += __shfl_xor(dnm, 16);
    dnm += __shfl_xor(dnm, 32);
#pragma unroll
    for (int k = 0; k < 8; ++k) {
        acc[k] += __shfl_xor(acc[k], 16);
        acc[k] += __shfl_xor(acc[k], 32);
    }
    // self-loop (uniform across quarters)
    {
        float p = __expf(lrelu(a_s1[wid * 4 + head] + ad));
        uint4 g0 = *(const uint4*)&h1b[(size_t)wid * 128 + c0];
        float2 ha = bfpair(g0.x), hb = bfpair(g0.y), hc = bfpair(g0.z), hd2 = bfpair(g0.w);
        dnm += p;
        acc[0] += p * ha.x;  acc[1] += p * ha.y;
        acc[2] += p * hb.x;  acc[3] += p * hb.y;
        acc[4] += p * hc.x;  acc[5] += p * hc.y;
        acc[6] += p * hd2.x; acc[7] += p * hd2.y;
    }
    float inv = 1.f / (dnm + 1e-16f);
    float r[8];
    float4 bva = *(const float4*)&b1[c0];
    float4 bvb = *(const float4*)&b1[c0 + 4];
    r[0] = fmaxf(acc[0] * inv + bva.x, 0.f);
    r[1] = fmaxf(acc[1] * inv + bva.y, 0.f);
    r[2] = fmaxf(acc[2] * inv + bva.z, 0.f);
    r[3] = fmaxf(acc[3] * inv + bva.w, 0.f);
    r[4] = fmaxf(acc[4] * inv + bvb.x, 0.f);
    r[5] = fmaxf(acc[5] * inv + bvb.y, 0.f);
    r[6] = fmaxf(acc[6] * inv + bvb.z, 0.f);
    r[7] = fmaxf(acc[7] * inv + bvb.w, 0.f);

    // fused layer-2 projection: h2[k] = sum_c relu_out[c] * W2[c][k]
    float p0 = 0.f, p1 = 0.f;
#pragma unroll
    for (int k = 0; k < 4; ++k) {
        float4 w = *(const float4*)&W2[c0 * 2 + k * 4];   // rows c0+2k, c0+2k+1
        p0 += r[2 * k] * w.x + r[2 * k + 1] * w.z;
        p1 += r[2 * k] * w.y + r[2 * k + 1] * w.w;
    }
#pragma unroll
    for (int off = 1; off < 16; off <<= 1) {
        p0 += __shfl_xor(p0, off);
        p1 += __shfl_xor(p1, off);
    }
    if (lane == 0) {
        pk[wid] = make_float4(p0, p1,
                              p0 * a_src2[0] + p1 * a_src2[1],
                              p0 * a_dst2[0] + p1 * a_dst2[1]);
    }
}

// ---------------------------------------------------------------------------
// K4: layer-2 softmax-aggregation (1 head, 2 ch) + bias + log_softmax.
// 16 lanes per node (4 nodes per wave); single pass, no max shift.
// ---------------------------------------------------------------------------
__global__ __launch_bounds__(256) void k4_agg2(
    const float4* __restrict__ pk, const int* __restrict__ row_start,
    const unsigned short* __restrict__ csr_src, const float* __restrict__ b2,
    float* __restrict__ out, int n) {
    const int g = blockIdx.x * blockDim.x + threadIdx.x;
    const int lane = threadIdx.x & 63;
    const int node = (g >> 6) * 4 + (lane >> 4);
    const int l16 = lane & 15;
    if (node >= n) return;
    const int rs = row_start[node];
    const int deg = row_start[node + 1] - rs;
    const float4 me = pk[node];
    const float ad = me.w;

    float dnm = 0.f, a0 = 0.f, a1 = 0.f;
    for (int j = l16; j < deg; j += 16) {
        int s = (int)csr_src[rs + j];
        float4 qv = pk[s];
        float p = __expf(lrelu(qv.z + ad));
        dnm += p;
        a0 += p * qv.x;
        a1 += p * qv.y;
    }
    if (l16 == 0) {   // self-loop
        float p = __expf(lrelu(me.z + ad));
        dnm += p;
        a0 += p * me.x;
        a1 += p * me.y;
    }
#pragma unroll
    for (int off = 1; off < 16; off <<= 1) {
        dnm += __shfl_xor(dnm, off);
        a0 += __shfl_xor(a0, off);
        a1 += __shfl_xor(a1, off);
    }
    if (l16 == 0) {
        float inv = 1.f / (dnm + 1e-16f);
        float o0 = a0 * inv + b2[0];
        float o1 = a1 * inv + b2[1];
        float m2 = fmaxf(o0, o1);
        float lse = m2 + logf(__expf(o0 - m2) + __expf(o1 - m2));
        out[node * 2 + 0] = o0 - lse;
        out[node * 2 + 1] = o1 - lse;
    }
}

// ---------------------------------------------------------------------------
extern "C" void kernel_launch(void* const* d_in, const int* in_sizes, int n_in,
                              void* d_out, int out_size, void* d_ws, size_t ws_size,
                              hipStream_t stream) {
    const float* x      = (const float*)d_in[0];
    const int*   ei     = (const int*)d_in[1];
    const float* W1     = (const float*)d_in[2];
    const float* a_src1 = (const float*)d_in[3];
    const float* a_dst1 = (const float*)d_in[4];
    const float* b1     = (const float*)d_in[5];
    const float* W2     = (const float*)d_in[6];
    const float* a_src2 = (const float*)d_in[7];
    const float* a_dst2 = (const float*)d_in[8];
    const float* b2     = (const float*)d_in[9];
    float* out = (float*)d_out;

    const int N = in_sizes[0] / 128;
    const int E = in_sizes[1] / 2;
    const int* e_src = ei;        // edge_index[0]
    const int* e_dst = ei + E;    // edge_index[1]

    const int NBUK = (N + BUKSZ - 1) >> BSH;     // 782 for N=50000
    const int nblk = (E + CHUNK - 1) / CHUNK;    // 196 for E=800000

    // ---- workspace carve (256B aligned)
    char* p = (char*)d_ws;
    auto alloc = [&](size_t bytes) -> void* {
        void* r = (void*)p;
        p += (bytes + 255) & ~(size_t)255;
        return r;
    };
    unsigned short* h1b   = (unsigned short*)alloc((size_t)N * 128 * 2);
    float*          a_s1  = (float*)alloc((size_t)N * 4 * 4);
    float*          a_d1  = (float*)alloc((size_t)N * 4 * 4);
    float4*         pk    = (float4*)alloc((size_t)N * 16);
    int*            mat   = (int*)alloc((size_t)NBUK * nblk * 4);
    int*            btot  = (int*)alloc((size_t)NBUK * 4);
    int*            bbase = (int*)alloc((size_t)(NBUK + 1) * 4);
    unsigned int*   part  = (unsigned int*)alloc((size_t)E * 4);
    int*            row_start = (int*)alloc(((size_t)NBUK * BUKSZ + 1) * 4);
    unsigned short* csr_src   = (unsigned short*)alloc((size_t)E * 2);

    k1_mfma<<<(N + 63) / 64, 256, 0, stream>>>(x, W1, a_src1, a_dst1, h1b, a_s1, a_d1, N);

    {   // fused CSR build (cooperative: grid-wide sync between phases)
        int  E_ = E, NBUK_ = NBUK, nblk_ = nblk;
        void* args[] = { (void*)&e_src, (void*)&e_dst, (void*)&E_, (void*)&NBUK_,
                         (void*)&nblk_, (void*)&mat, (void*)&btot, (void*)&bbase,
                         (void*)&part, (void*)&row_start, (void*)&csr_src };
        hipLaunchCooperativeKernel((const void*)k_part, dim3(nblk), dim3(256),
                                   args, 0, stream);
    }

    k3_agg1<<<(N * 64 + 255) / 256, 256, 0, stream>>>(h1b, a_s1, a_d1, row_start, csr_src,
                                                      b1, W2, a_src2, a_dst2, pk, N);
    k4_agg2<<<((N + 3) / 4 * 64 + 255) / 256, 256, 0, stream>>>(pk, row_start, csr_src,
                                                                b2, out, N);
}

// Round 9
// 205.457 us; speedup vs baseline: 1.6673x; 1.6673x over previous
//
#include <hip/hip_runtime.h>
#include <hip/hip_bf16.h>

#define NEG_SLOPE 0.2f
#define BSH   6        // bucket = 64 dst nodes
#define BUKSZ 64
#define MAXBUK 1024    // supports N <= 65536 (and src ids fit in ushort); 4*256
#define CHUNK 4096     // edges per partition block
#define BCAP  2048     // LDS capacity per bucket in csr kernel (mean ~1024, 2x headroom)
#define XPAD  136      // LDS row stride (128 + 8): 272 B rows, 16B-aligned, breaks bank aliasing

typedef __attribute__((ext_vector_type(8))) short bf16x8;   // 8 bf16 = 4 VGPRs
typedef __attribute__((ext_vector_type(4))) float f32x4;    // MFMA C/D

__device__ __forceinline__ float lrelu(float v) {
    return v > 0.f ? v : NEG_SLOPE * v;
}

__device__ __forceinline__ unsigned short f2bf(float f) {   // RNE float->bf16
    unsigned int u = __float_as_uint(f);
    u = (u + 0x7fffu + ((u >> 16) & 1u)) >> 16;
    return (unsigned short)u;
}

__device__ __forceinline__ float2 bfpair(unsigned int u) {  // 2 packed bf16 -> 2 floats
    float2 r;
    r.x = __uint_as_float(u << 16);
    r.y = __uint_as_float(u & 0xffff0000u);
    return r;
}

// ---------------------------------------------------------------------------
// K1_FAT: blocks [0, nblk) do the edge-bucket histogram (mat[chunk][bucket]);
// blocks [nblk, nblk+gemmBlocks) do the MFMA GEMM h1b = x @ W1 (bf16 out)
// with fused a_s1/a_d1 epilogue. Independent inputs -> safe fusion; hist
// overlaps the MFMA work and saves one dispatch + gap.
// ---------------------------------------------------------------------------
__global__ __launch_bounds__(256) void k1_fat(const float* __restrict__ x,
                                              const float* __restrict__ W1,
                                              const float* __restrict__ a_src1,
                                              const float* __restrict__ a_dst1,
                                              unsigned short* __restrict__ h1b,
                                              float* __restrict__ a_s1,
                                              float* __restrict__ a_d1, int n,
                                              const int* __restrict__ e_dst, int e,
                                              int nbuk, int nblk,
                                              int* __restrict__ mat) {
    __shared__ unsigned short xsh[64 * XPAD];    // x tile bf16 (17.4 KB)
    __shared__ unsigned short wsh[128 * XPAD];   // W1^T bf16 (34.8 KB)
    const int tid = threadIdx.x;

    if (blockIdx.x < (unsigned)nblk) {
        // ---------------- histogram path ----------------
        int* lcnt = (int*)xsh;                   // reuse LDS
        const int bid = blockIdx.x;
        for (int b = tid; b < nbuk; b += 256) lcnt[b] = 0;
        __syncthreads();
        const int e0 = bid * CHUNK;
        const int e1 = min(e, e0 + CHUNK);
        for (int k = e0 + tid; k < e1; k += 256)
            atomicAdd(&lcnt[e_dst[k] >> BSH], 1);
        __syncthreads();
        for (int b = tid; b < nbuk; b += 256)
            mat[bid * nbuk + b] = lcnt[b];       // coalesced row write
        return;
    }

    // ---------------- GEMM path ----------------
    const int row0 = (blockIdx.x - nblk) * 64;
    // stage W1 -> wsh[n*XPAD+k] (coalesced fp32 read; L2-resident)
    for (int i = tid; i < 128 * 128; i += 256) {
        int k = i >> 7, nn = i & 127;
        wsh[nn * XPAD + k] = f2bf(W1[i]);
    }
    // stage x: 64 rows x 128 k, fp32 -> bf16 (8 float4 per thread)
#pragma unroll
    for (int i = 0; i < 8; ++i) {
        int idx = tid + i * 256;          // float4 index 0..2047 (32 per row)
        int r = idx >> 5;
        int c = (idx & 31) * 4;
        int gr = row0 + r;
        float4 v = make_float4(0.f, 0.f, 0.f, 0.f);
        if (gr < n) v = *(const float4*)&x[(size_t)gr * 128 + c];
        ushort4 b;
        b.x = f2bf(v.x); b.y = f2bf(v.y); b.z = f2bf(v.z); b.w = f2bf(v.w);
        *(ushort4*)&xsh[r * XPAD + c] = b;
    }
    __syncthreads();

    const int wave = tid >> 6;
    const int lane = tid & 63;
    const int quad = lane >> 4;
    const int l16 = lane & 15;

    // A fragments: m = l16 (row within wave strip), k = ks*32 + quad*8
    bf16x8 afrag[4];
#pragma unroll
    for (int ks = 0; ks < 4; ++ks)
        afrag[ks] = *(const bf16x8*)&xsh[(wave * 16 + l16) * XPAD + ks * 32 + quad * 8];

    f32x4 acc[8];
#pragma unroll
    for (int t = 0; t < 8; ++t) acc[t] = (f32x4){0.f, 0.f, 0.f, 0.f};

#pragma unroll
    for (int t = 0; t < 8; ++t) {         // n-tiles: cols t*16 .. t*16+15
#pragma unroll
        for (int ks = 0; ks < 4; ++ks) {
            bf16x8 bfrag = *(const bf16x8*)&wsh[(t * 16 + l16) * XPAD + ks * 32 + quad * 8];
            acc[t] = __builtin_amdgcn_mfma_f32_16x16x32_bf16(afrag[ks], bfrag, acc[t], 0, 0, 0);
        }
    }

    // --- attention-dot epilogue (fp32 from accumulators) ---
    float hs[4][4], hd[4][4];             // [head][reg]
#pragma unroll
    for (int h = 0; h < 4; ++h)
#pragma unroll
        for (int r = 0; r < 4; ++r) { hs[h][r] = 0.f; hd[h][r] = 0.f; }
#pragma unroll
    for (int t = 0; t < 8; ++t) {
        float as = a_src1[t * 16 + l16];
        float advv = a_dst1[t * 16 + l16];
#pragma unroll
        for (int r = 0; r < 4; ++r) {
            float ps = acc[t][r] * as;
            float pd = acc[t][r] * advv;
#pragma unroll
            for (int off = 1; off < 16; off <<= 1) {
                ps += __shfl_xor(ps, off);
                pd += __shfl_xor(pd, off);
            }
            hs[t >> 1][r] += ps;
            hd[t >> 1][r] += pd;
        }
    }
    if (l16 < 4) {                        // lane l16 writes head h=l16
        int h = l16;
#pragma unroll
        for (int r = 0; r < 4; ++r) {
            int gr = row0 + wave * 16 + quad * 4 + r;
            if (gr < n) {
                a_s1[gr * 4 + h] = hs[h][r];
                a_d1[gr * 4 + h] = hd[h][r];
            }
        }
    }

    // --- h1b store via LDS (coalesced ushort4) ---
    __syncthreads();                      // xsh dead (afrag consumed)
#pragma unroll
    for (int t = 0; t < 8; ++t)
#pragma unroll
        for (int r = 0; r < 4; ++r)
            xsh[(wave * 16 + quad * 4 + r) * XPAD + t * 16 + l16] = f2bf(acc[t][r]);
    __syncthreads();
#pragma unroll
    for (int i = 0; i < 8; ++i) {
        int idx = tid + i * 256;          // ushort4 index 0..2047 (32 per row)
        int r = idx >> 5;
        int c = (idx & 31) * 4;
        int gr = row0 + r;
        if (gr < n)
            *(ushort4*)&h1b[(size_t)gr * 128 + c] = *(ushort4*)&xsh[r * XPAD + c];
    }
}

// Column scan: mat[i][b] -> exclusive over i (in place); column totals -> btot[b]
__global__ __launch_bounds__(256) void kc_colscan(int* __restrict__ mat, int nbuk, int nblk,
                                                  int* __restrict__ btot) {
    int b = blockIdx.x * 256 + threadIdx.x;
    if (b >= nbuk) return;
    int run = 0;
#pragma unroll 4
    for (int i = 0; i < nblk; ++i) {
        int idx = i * nbuk + b;
        int t = mat[idx];
        mat[idx] = run;
        run += t;
    }
    btot[b] = run;
}

// ---------------------------------------------------------------------------
// Placement + redundant bucket scan: each block recomputes the exclusive scan
// of btot[0..nbuk) in LDS (L2-hot, ~2 us) -> no separate bucketscan kernel,
// no grid sync. Block 0 publishes bbase for the csr kernel (launched after).
// ---------------------------------------------------------------------------
__global__ __launch_bounds__(256) void kb_place2(const int* __restrict__ src,
                                                 const int* __restrict__ dst, int e,
                                                 int nbuk, const int* __restrict__ mat,
                                                 const int* __restrict__ btot,
                                                 unsigned int* __restrict__ part,
                                                 int* __restrict__ bbase) {
    __shared__ int lbase[MAXBUK];         // exclusive bucket bases
    __shared__ int s[256];
    const int tid = threadIdx.x;
    const int bid = blockIdx.x;
    // 4 elements per thread: local prefix + block scan
    int t4 = tid * 4;
    int v0 = (t4     < nbuk) ? btot[t4]     : 0;
    int v1 = (t4 + 1 < nbuk) ? btot[t4 + 1] : 0;
    int v2 = (t4 + 2 < nbuk) ? btot[t4 + 2] : 0;
    int v3 = (t4 + 3 < nbuk) ? btot[t4 + 3] : 0;
    int ssum = v0 + v1 + v2 + v3;
    s[tid] = ssum;
    __syncthreads();
    for (int off = 1; off < 256; off <<= 1) {
        int t = (tid >= off) ? s[tid - off] : 0;
        __syncthreads();
        s[tid] += t;
        __syncthreads();
    }
    int excl = s[tid] - ssum;
    if (t4 < nbuk)     lbase[t4]     = excl;
    if (t4 + 1 < nbuk) lbase[t4 + 1] = excl + v0;
    if (t4 + 2 < nbuk) lbase[t4 + 2] = excl + v0 + v1;
    if (t4 + 3 < nbuk) lbase[t4 + 3] = excl + v0 + v1 + v2;
    __syncthreads();
    if (bid == 0) {                       // publish for kc_csr (runs after)
        for (int b = tid; b < nbuk; b += 256) bbase[b] = lbase[b];
        if (tid == 255) bbase[nbuk] = s[255];
    }
    // seed cursors: lbase[b] += mat[bid][b]  (becomes this chunk's cursor)
    for (int b = tid; b < nbuk; b += 256)
        lbase[b] += mat[bid * nbuk + b];
    __syncthreads();
    const int e0 = bid * CHUNK;
    const int e1 = min(e, e0 + CHUNK);
    for (int k = e0 + tid; k < e1; k += 256) {
        int d = dst[k];
        int pos = atomicAdd(&lbase[d >> BSH], 1);
        part[pos] = ((unsigned int)src[k] << 16) | (unsigned int)(d & 0xffff);
    }
}

// ---------------------------------------------------------------------------
// CSR finalize: block per bucket -> row_start (int, absolute) + csr_src (ushort)
// ---------------------------------------------------------------------------
__global__ __launch_bounds__(256) void kc_csr(const unsigned int* __restrict__ part,
                                              const int* __restrict__ bbase, int nbuk,
                                              int* __restrict__ row_start,
                                              unsigned short* __restrict__ csr_src) {
    __shared__ unsigned short ls[BCAP];
    __shared__ int cnt[64];
    __shared__ int cur[64];
    const int b = blockIdx.x;
    const int tid = threadIdx.x;
    const int eb = bbase[b];
    const int nE = bbase[b + 1] - eb;
    if (tid < 64) cnt[tid] = 0;
    __syncthreads();
    for (int k = tid; k < nE; k += 256)
        atomicAdd(&cnt[part[eb + k] & 63u], 1);
    __syncthreads();
    if (tid < 64) {                       // wave-0 exclusive scan of 64 counts
        int v = cnt[tid];
        int incl = v;
#pragma unroll
        for (int off = 1; off < 64; off <<= 1) {
            int t = __shfl_up(incl, off);
            if (tid >= off) incl += t;
        }
        int excl = incl - v;
        cur[tid] = excl;
        row_start[(b << BSH) + tid] = eb + excl;
        if (tid == 63 && b == nbuk - 1) row_start[(b << BSH) + 64] = eb + incl;
    }
    __syncthreads();
    for (int k = tid; k < nE; k += 256) {
        unsigned int u = part[eb + k];
        int pos = atomicAdd(&cur[u & 63u], 1);
        if (pos < BCAP) ls[pos] = (unsigned short)(u >> 16);
    }
    __syncthreads();
    for (int k = tid; k < nE; k += 256)
        csr_src[eb + k] = ls[k];          // coalesced
}

// ---------------------------------------------------------------------------
// K3: layer-1 softmax-aggregation, flat: one wave per dst node.
// Quarter-wave per edge, PREDICATED uniform unroll-4 (16 gather chains/wave;
// pad slots clamp to deg-1 with zero weight -> no divergent tail).
// Lane owns 8 bf16 channels (16B gather). No max shift (logits bounded).
// Fused: +bias, relu, layer-2 projection, layer-2 attn dots -> pk.
// ---------------------------------------------------------------------------
__global__ __launch_bounds__(256) void k3_agg1(
    const unsigned short* __restrict__ h1b, const float* __restrict__ a_s1,
    const float* __restrict__ a_d1, const int* __restrict__ row_start,
    const unsigned short* __restrict__ csr_src, const float* __restrict__ b1,
    const float* __restrict__ W2, const float* __restrict__ a_src2,
    const float* __restrict__ a_dst2, float4* __restrict__ pk, int n) {
    const int wid = (blockIdx.x * blockDim.x + threadIdx.x) >> 6;
    const int lane = threadIdx.x & 63;
    if (wid >= n) return;
    const int q = lane >> 4;             // quarter: edge slot 0..3
    const int l16 = lane & 15;
    const int c0 = l16 * 8;              // 8 channels per lane
    const int head = l16 >> 2;           // 4 lanes per head
    const int rs = row_start[wid];
    const int deg = row_start[wid + 1] - rs;
    const float ad = a_d1[wid * 4 + head];

    float dnm = 0.f;
    float acc[8] = {};
    const int dm1 = deg - 1;
    const int rounded = (deg + 15) & ~15;
    for (int j = q; j < rounded; j += 16) {   // 4 predicated slots per quarter
        int i0 = min(j,      dm1);
        int i1 = min(j + 4,  dm1);
        int i2 = min(j + 8,  dm1);
        int i3 = min(j + 12, dm1);
        int s0 = (int)csr_src[rs + i0];
        int s1 = (int)csr_src[rs + i1];
        int s2 = (int)csr_src[rs + i2];
        int s3 = (int)csr_src[rs + i3];
        float as0 = a_s1[s0 * 4 + head];
        float as1 = a_s1[s1 * 4 + head];
        float as2 = a_s1[s2 * 4 + head];
        float as3 = a_s1[s3 * 4 + head];
        uint4 g0 = *(const uint4*)&h1b[(size_t)s0 * 128 + c0];
        uint4 g1 = *(const uint4*)&h1b[(size_t)s1 * 128 + c0];
        uint4 g2 = *(const uint4*)&h1b[(size_t)s2 * 128 + c0];
        uint4 g3 = *(const uint4*)&h1b[(size_t)s3 * 128 + c0];
        float p0 = (j      < deg) ? __expf(lrelu(as0 + ad)) : 0.f;
        float p1 = (j + 4  < deg) ? __expf(lrelu(as1 + ad)) : 0.f;
        float p2 = (j + 8  < deg) ? __expf(lrelu(as2 + ad)) : 0.f;
        float p3 = (j + 12 < deg) ? __expf(lrelu(as3 + ad)) : 0.f;
        dnm += (p0 + p1) + (p2 + p3);
        float2 v0a = bfpair(g0.x), v0b = bfpair(g0.y), v0c = bfpair(g0.z), v0d = bfpair(g0.w);
        float2 v1a = bfpair(g1.x), v1b = bfpair(g1.y), v1c = bfpair(g1.z), v1d = bfpair(g1.w);
        float2 v2a = bfpair(g2.x), v2b = bfpair(g2.y), v2c = bfpair(g2.z), v2d = bfpair(g2.w);
        float2 v3a = bfpair(g3.x), v3b = bfpair(g3.y), v3c = bfpair(g3.z), v3d = bfpair(g3.w);
        acc[0] += (p0 * v0a.x + p1 * v1a.x) + (p2 * v2a.x + p3 * v3a.x);
        acc[1] += (p0 * v0a.y + p1 * v1a.y) + (p2 * v2a.y + p3 * v3a.y);
        acc[2] += (p0 * v0b.x + p1 * v1b.x) + (p2 * v2b.x + p3 * v3b.x);
        acc[3] += (p0 * v0b.y + p1 * v1b.y) + (p2 * v2b.y + p3 * v3b.y);
        acc[4] += (p0 * v0c.x + p1 * v1c.x) + (p2 * v2c.x + p3 * v3c.x);
        acc[5] += (p0 * v0c.y + p1 * v1c.y) + (p2 * v2c.y + p3 * v3c.y);
        acc[6] += (p0 * v0d.x + p1 * v1d.x) + (p2 * v2d.x + p3 * v3d.x);
        acc[7] += (p0 * v0d.y + p1 * v1d.y) + (p2 * v2d.y + p3 * v3d.y);
    }
    // combine quarters (lanes l16, l16+16, l16+32, l16+48 share channels/head)
    dnm += __shfl_xor(dnm, 16);
    dnm += __shfl_xor(dnm, 32);
#pragma unroll
    for (int k = 0; k < 8; ++k) {
        acc[k] += __shfl_xor(acc[k], 16);
        acc[k] += __shfl_xor(acc[k], 32);
    }
    // self-loop (uniform across quarters)
    {
        float p = __expf(lrelu(a_s1[wid * 4 + head] + ad));
        uint4 g0 = *(const uint4*)&h1b[(size_t)wid * 128 + c0];
        float2 ha = bfpair(g0.x), hb = bfpair(g0.y), hc = bfpair(g0.z), hd2 = bfpair(g0.w);
        dnm += p;
        acc[0] += p * ha.x;  acc[1] += p * ha.y;
        acc[2] += p * hb.x;  acc[3] += p * hb.y;
        acc[4] += p * hc.x;  acc[5] += p * hc.y;
        acc[6] += p * hd2.x; acc[7] += p * hd2.y;
    }
    float inv = 1.f / (dnm + 1e-16f);
    float r[8];
    float4 bva = *(const float4*)&b1[c0];
    float4 bvb = *(const float4*)&b1[c0 + 4];
    r[0] = fmaxf(acc[0] * inv + bva.x, 0.f);
    r[1] = fmaxf(acc[1] * inv + bva.y, 0.f);
    r[2] = fmaxf(acc[2] * inv + bva.z, 0.f);
    r[3] = fmaxf(acc[3] * inv + bva.w, 0.f);
    r[4] = fmaxf(acc[4] * inv + bvb.x, 0.f);
    r[5] = fmaxf(acc[5] * inv + bvb.y, 0.f);
    r[6] = fmaxf(acc[6] * inv + bvb.z, 0.f);
    r[7] = fmaxf(acc[7] * inv + bvb.w, 0.f);

    // fused layer-2 projection: h2[k] = sum_c relu_out[c] * W2[c][k]
    float p0 = 0.f, p1 = 0.f;
#pragma unroll
    for (int k = 0; k < 4; ++k) {
        float4 w = *(const float4*)&W2[c0 * 2 + k * 4];   // rows c0+2k, c0+2k+1
        p0 += r[2 * k] * w.x + r[2 * k + 1] * w.z;
        p1 += r[2 * k] * w.y + r[2 * k + 1] * w.w;
    }
#pragma unroll
    for (int off = 1; off < 16; off <<= 1) {
        p0 += __shfl_xor(p0, off);
        p1 += __shfl_xor(p1, off);
    }
    if (lane == 0) {
        pk[wid] = make_float4(p0, p1,
                              p0 * a_src2[0] + p1 * a_src2[1],
                              p0 * a_dst2[0] + p1 * a_dst2[1]);
    }
}

// ---------------------------------------------------------------------------
// K4: layer-2 softmax-aggregation (1 head, 2 ch) + bias + log_softmax.
// 16 lanes per node (4 nodes per wave); single pass, no max shift.
// ---------------------------------------------------------------------------
__global__ __launch_bounds__(256) void k4_agg2(
    const float4* __restrict__ pk, const int* __restrict__ row_start,
    const unsigned short* __restrict__ csr_src, const float* __restrict__ b2,
    float* __restrict__ out, int n) {
    const int g = blockIdx.x * blockDim.x + threadIdx.x;
    const int lane = threadIdx.x & 63;
    const int node = (g >> 6) * 4 + (lane >> 4);
    const int l16 = lane & 15;
    if (node >= n) return;
    const int rs = row_start[node];
    const int deg = row_start[node + 1] - rs;
    const float4 me = pk[node];
    const float ad = me.w;

    float dnm = 0.f, a0 = 0.f, a1 = 0.f;
    for (int j = l16; j < deg; j += 16) {
        int s = (int)csr_src[rs + j];
        float4 qv = pk[s];
        float p = __expf(lrelu(qv.z + ad));
        dnm += p;
        a0 += p * qv.x;
        a1 += p * qv.y;
    }
    if (l16 == 0) {   // self-loop
        float p = __expf(lrelu(me.z + ad));
        dnm += p;
        a0 += p * me.x;
        a1 += p * me.y;
    }
#pragma unroll
    for (int off = 1; off < 16; off <<= 1) {
        dnm += __shfl_xor(dnm, off);
        a0 += __shfl_xor(a0, off);
        a1 += __shfl_xor(a1, off);
    }
    if (l16 == 0) {
        float inv = 1.f / (dnm + 1e-16f);
        float o0 = a0 * inv + b2[0];
        float o1 = a1 * inv + b2[1];
        float m2 = fmaxf(o0, o1);
        float lse = m2 + logf(__expf(o0 - m2) + __expf(o1 - m2));
        out[node * 2 + 0] = o0 - lse;
        out[node * 2 + 1] = o1 - lse;
    }
}

// ---------------------------------------------------------------------------
extern "C" void kernel_launch(void* const* d_in, const int* in_sizes, int n_in,
                              void* d_out, int out_size, void* d_ws, size_t ws_size,
                              hipStream_t stream) {
    const float* x      = (const float*)d_in[0];
    const int*   ei     = (const int*)d_in[1];
    const float* W1     = (const float*)d_in[2];
    const float* a_src1 = (const float*)d_in[3];
    const float* a_dst1 = (const float*)d_in[4];
    const float* b1     = (const float*)d_in[5];
    const float* W2     = (const float*)d_in[6];
    const float* a_src2 = (const float*)d_in[7];
    const float* a_dst2 = (const float*)d_in[8];
    const float* b2     = (const float*)d_in[9];
    float* out = (float*)d_out;

    const int N = in_sizes[0] / 128;
    const int E = in_sizes[1] / 2;
    const int* e_src = ei;        // edge_index[0]
    const int* e_dst = ei + E;    // edge_index[1]

    const int NBUK = (N + BUKSZ - 1) >> BSH;     // 782 for N=50000
    const int nblk = (E + CHUNK - 1) / CHUNK;    // 196 for E=800000
    const int gemmBlocks = (N + 63) / 64;        // 782

    // ---- workspace carve (256B aligned)
    char* p = (char*)d_ws;
    auto alloc = [&](size_t bytes) -> void* {
        void* r = (void*)p;
        p += (bytes + 255) & ~(size_t)255;
        return r;
    };
    unsigned short* h1b   = (unsigned short*)alloc((size_t)N * 128 * 2);
    float*          a_s1  = (float*)alloc((size_t)N * 4 * 4);
    float*          a_d1  = (float*)alloc((size_t)N * 4 * 4);
    float4*         pk    = (float4*)alloc((size_t)N * 16);
    int*            mat   = (int*)alloc((size_t)NBUK * nblk * 4);
    int*            btot  = (int*)alloc((size_t)NBUK * 4);
    int*            bbase = (int*)alloc((size_t)(NBUK + 1) * 4);
    unsigned int*   part  = (unsigned int*)alloc((size_t)E * 4);
    int*            row_start = (int*)alloc(((size_t)NBUK * BUKSZ + 1) * 4);
    unsigned short* csr_src   = (unsigned short*)alloc((size_t)E * 2);

    k1_fat<<<nblk + gemmBlocks, 256, 0, stream>>>(x, W1, a_src1, a_dst1, h1b, a_s1, a_d1, N,
                                                  e_dst, E, NBUK, nblk, mat);
    kc_colscan<<<(NBUK + 255) / 256, 256, 0, stream>>>(mat, NBUK, nblk, btot);
    kb_place2<<<nblk, 256, 0, stream>>>(e_src, e_dst, E, NBUK, mat, btot, part, bbase);
    kc_csr<<<NBUK, 256, 0, stream>>>(part, bbase, NBUK, row_start, csr_src);

    k3_agg1<<<(N * 64 + 255) / 256, 256, 0, stream>>>(h1b, a_s1, a_d1, row_start, csr_src,
                                                      b1, W2, a_src2, a_dst2, pk, N);
    k4_agg2<<<((N + 3) / 4 * 64 + 255) / 256, 256, 0, stream>>>(pk, row_start, csr_src,
                                                                b2, out, N);
}